// Round 3
// baseline (112.806 us; speedup 1.0000x reference)
//
#include <hip/hip_runtime.h>

#define BATCH 2048
#define MUL 128
#define NTRI 165
#define NPAIR 45
#define KTOT 224          // 14 k-steps of 16
#define KPAD 232          // ushort row stride (464 B)
#define NCOL 96
#define NSTEP 14

typedef __attribute__((ext_vector_type(8))) short s16x8;
typedef __attribute__((ext_vector_type(16))) float f32x16;
typedef __attribute__((ext_vector_type(4))) int i32x4;

// ---- compile-time tables ----
struct TriTab { unsigned char a[NTRI], b[NTRI], c[NTRI]; };
constexpr TriTab make_tri() {
  TriTab t{}; int q = 0;
  for (int a = 0; a < 9; a++) for (int b = a; b < 9; b++) for (int c = b; c < 9; c++) {
    t.a[q] = (unsigned char)a; t.b[q] = (unsigned char)b; t.c[q] = (unsigned char)c; q++;
  }
  return t;
}
constexpr TriTab TRI = make_tri();

struct PairTab { unsigned char a[NPAIR], b[NPAIR]; unsigned char idx[9][9]; };
constexpr PairTab make_pair() {
  PairTab t{}; int q = 0;
  for (int a = 0; a < 9; a++) for (int b = a; b < 9; b++) {
    t.a[q] = (unsigned char)a; t.b[q] = (unsigned char)b;
    t.idx[a][b] = (unsigned char)q; t.idx[b][a] = (unsigned char)q; q++;
  }
  return t;
}
constexpr PairTab PAIR = make_pair();

struct KTab { unsigned char pi[NTRI], xi[NTRI]; };  // triple slots: pair idx + third x
constexpr KTab make_kt() {
  KTab t{};
  for (int q = 0; q < NTRI; q++) {
    t.pi[q] = PAIR.idx[TRI.a[q]][TRI.b[q]];
    t.xi[q] = TRI.c[q];
  }
  return t;
}
constexpr KTab KT = make_kt();

// ---- prep: build bf16 B-matrix [n=96][k padded to 232] from symmetrized U ----
__global__ void prep_kernel(const float* __restrict__ U30, const float* __restrict__ U20, const float* __restrict__ U10,
                            const float* __restrict__ U31, const float* __restrict__ U21, const float* __restrict__ U11,
                            const float* __restrict__ U32, const float* __restrict__ U22, const float* __restrict__ U12,
                            unsigned short* __restrict__ wsB) {
  int t = blockIdx.x * blockDim.x + threadIdx.x;
  if (t >= NCOL * KPAD) return;
  int n = t / KPAD, k = t % KPAD;
  const float* U3[3] = {U30, U31, U32};
  const float* U2[3] = {U20, U21, U22};
  const float* U1[3] = {U10, U11, U12};
  float val = 0.f;
  if (n < 54) {
    if (k < NTRI) {
      int o = n / 6, j3 = n % 6;
      int ir = (o > 0) + (o > 3); int lo = o - (ir == 1 ? 1 : (ir == 2 ? 4 : 0));
      int a = 0, b = 0, cc = 0;
      { int idx = 0; bool done = false;
        for (int A = 0; A < 9 && !done; A++) for (int B = A; B < 9 && !done; B++) for (int C = B; C < 9 && !done; C++) {
          if (idx == k) { a = A; b = B; cc = C; done = true; } idx++; } }
      int pm[6][3] = {{a,b,cc},{a,cc,b},{b,a,cc},{b,cc,a},{cc,a,b},{cc,b,a}};
      for (int p = 0; p < 6; p++) {
        bool dup = false;
        for (int rr = 0; rr < p; rr++)
          if (pm[rr][0] == pm[p][0] && pm[rr][1] == pm[p][1] && pm[rr][2] == pm[p][2]) dup = true;
        if (!dup) val += U3[ir][(((lo * 9 + pm[p][0]) * 9 + pm[p][1]) * 9 + pm[p][2]) * 6 + j3];
      }
    }
  } else if (n < 81) {
    if (k >= NTRI && k < NTRI + NPAIR) {
      int o = (n - 54) / 3, j2 = (n - 54) % 3;
      int ir = (o > 0) + (o > 3); int lo = o - (ir == 1 ? 1 : (ir == 2 ? 4 : 0));
      int p = k - NTRI;
      int a = 0, b = 0;
      { int idx = 0; bool done = false;
        for (int A = 0; A < 9 && !done; A++) for (int B = A; B < 9 && !done; B++) {
          if (idx == p) { a = A; b = B; done = true; } idx++; } }
      val = U2[ir][((lo * 9 + a) * 9 + b) * 3 + j2];
      if (a != b) val += U2[ir][((lo * 9 + b) * 9 + a) * 3 + j2];
    }
  } else if (n < 90) {
    if (k >= 210 && k < 219) {
      int o = n - 81;
      int ir = (o > 0) + (o > 3); int lo = o - (ir == 1 ? 1 : (ir == 2 ? 4 : 0));
      val = U1[ir][lo * 9 + (k - 210)];
    }
  }
  unsigned u = __float_as_uint(val);
  unsigned r = (u + 0x7FFFu + ((u >> 16) & 1u)) >> 16;   // RNE to bf16
  wsB[t] = (unsigned short)r;
}

// ---- main: one block per batch row b; 4 waves; wave = one 32-row strip ----
__global__ __launch_bounds__(256) void symcon_mfma(
    const float* __restrict__ x, const int* __restrict__ indices,
    const float* __restrict__ w, const unsigned short* __restrict__ wsB,
    float* __restrict__ out)
{
  __shared__ __align__(16) unsigned short Bt[NCOL * KPAD];   // 44544 B
  __shared__ float epi[4][8 * 104];                          // 13312 B

  const int tid = threadIdx.x;
  {
    const i32x4* src = (const i32x4*)wsB;
    i32x4* dst = (i32x4*)Bt;
    const int nv = (NCOL * KPAD) / 8;   // 2784 16B-chunks
    for (int i = tid; i < nv; i += 256) dst[i] = src[i];
  }
  __syncthreads();

  const int wave = tid >> 6;
  const int l = tid & 63;
  const int l5 = l & 31;
  const int g2 = l >> 5;
  const int row0 = blockIdx.x * 128 + wave * 32;
  const int e = indices[blockIdx.x];

  // per-lane x row and pair products (row = row0 + l5; both lane-halves same rows)
  const float* xp = x + (size_t)(row0 + l5) * 9;
  float xx[9];
#pragma unroll
  for (int i = 0; i < 9; i++) xx[i] = xp[i];
  float pr[NPAIR];
#pragma unroll
  for (int p = 0; p < NPAIR; p++) pr[p] = xx[PAIR.a[p]] * xx[PAIR.b[p]];

  f32x16 acc[3];
#pragma unroll
  for (int ct = 0; ct < 3; ct++)
#pragma unroll
    for (int i = 0; i < 16; i++) acc[ct][i] = 0.f;

#pragma unroll
  for (int s = 0; s < NSTEP; s++) {
    // all lanes compute this k-step's 16 monomials (compile-time indices)
    float m[16];
#pragma unroll
    for (int t = 0; t < 16; t++) {
      const int k = s * 16 + t;
      if (k < NTRI)                m[t] = pr[KT.pi[k]] * xx[KT.xi[k]];
      else if (k < NTRI + NPAIR)   m[t] = pr[k - NTRI];
      else if (k < 219)            m[t] = xx[k - 210];
      else                         m[t] = 0.f;
    }
    // select this lane-half's 8 slots, pack to bf16
    unsigned pk[4];
#pragma unroll
    for (int u = 0; u < 4; u++) {
      float lo = g2 ? m[8 + 2 * u]     : m[2 * u];
      float hi = g2 ? m[8 + 2 * u + 1] : m[2 * u + 1];
      asm("v_cvt_pk_bf16_f32 %0, %1, %2" : "=v"(pk[u]) : "v"(lo), "v"(hi));
    }
    i32x4 ai;
    ai[0] = (int)pk[0]; ai[1] = (int)pk[1]; ai[2] = (int)pk[2]; ai[3] = (int)pk[3];
    s16x8 af = __builtin_bit_cast(s16x8, ai);
#pragma unroll
    for (int ct = 0; ct < 3; ct++) {
      i32x4 bi = *(const i32x4*)((const char*)Bt + 464 * (ct * 32 + l5) + 32 * s + 16 * g2);
      s16x8 bf = __builtin_bit_cast(s16x8, bi);
      acc[ct] = __builtin_amdgcn_mfma_f32_32x32x16_bf16(af, bf, acc[ct], 0, 0, 0);
    }
  }

  // ---- epilogue: per reg-quad (8 rows), LDS transpose + weight dot ----
  float* buf = epi[wave];
  const float* wbase = w + (size_t)e * 30 * 128;
#pragma unroll
  for (int q = 0; q < 4; q++) {
    // C layout: col = ct*32 + (lane&31); row = (reg&3) + 8*(reg>>2) + 4*(lane>>5)
#pragma unroll
    for (int ct = 0; ct < 3; ct++)
#pragma unroll
      for (int t2 = 0; t2 < 4; t2++)
        buf[(t2 + 4 * g2) * 104 + ct * 32 + l5] = acc[ct][4 * q + t2];
    __syncthreads();
    {
      const int r = l & 7, o = l >> 3;                 // 64 lanes: (row, o) for o=0..7
      const int c = (wave * 32 + 8 * q + r) & 127;
      const int ir = (o > 0) + (o > 3);
      const float* wp = wbase + ir * 10 * 128 + c;
      const float* br = buf + r * 104;
      float sum = 0.f;
#pragma unroll
      for (int k3 = 0; k3 < 6; k3++) sum = fmaf(br[6 * o + k3], wp[k3 * 128], sum);
#pragma unroll
      for (int k2 = 0; k2 < 3; k2++) sum = fmaf(br[54 + 3 * o + k2], wp[(6 + k2) * 128], sum);
      sum = fmaf(br[81 + o], wp[9 * 128], sum);
      const int col = (o == 0) ? c : (o < 4 ? 128 + 3 * c + (o - 1) : 512 + 5 * c + (o - 4));
      out[(size_t)blockIdx.x * 1152 + col] = sum;
      if (l < 8) {                                      // o = 8 overflow pass
        const int r8 = l;
        const int c8 = (wave * 32 + 8 * q + r8) & 127;
        const float* wp8 = wbase + 2 * 10 * 128 + c8;
        const float* br8 = buf + r8 * 104;
        float s8 = 0.f;
#pragma unroll
        for (int k3 = 0; k3 < 6; k3++) s8 = fmaf(br8[48 + k3], wp8[k3 * 128], s8);
#pragma unroll
        for (int k2 = 0; k2 < 3; k2++) s8 = fmaf(br8[78 + k2], wp8[(6 + k2) * 128], s8);
        s8 = fmaf(br8[89], wp8[9 * 128], s8);
        out[(size_t)blockIdx.x * 1152 + 512 + 5 * c8 + 4] = s8;
      }
    }
    __syncthreads();
  }
}

extern "C" void kernel_launch(void* const* d_in, const int* in_sizes, int n_in,
                              void* d_out, int out_size, void* d_ws, size_t ws_size,
                              hipStream_t stream) {
  const float* x   = (const float*)d_in[0];
  const int*   idx = (const int*)d_in[1];
  const float* w   = (const float*)d_in[2];
  const float* U30 = (const float*)d_in[3];
  const float* U20 = (const float*)d_in[4];
  const float* U10 = (const float*)d_in[5];
  const float* U31 = (const float*)d_in[6];
  const float* U21 = (const float*)d_in[7];
  const float* U11 = (const float*)d_in[8];
  const float* U32 = (const float*)d_in[9];
  const float* U22 = (const float*)d_in[10];
  const float* U12 = (const float*)d_in[11];
  unsigned short* wsB = (unsigned short*)d_ws;
  float* out = (float*)d_out;

  prep_kernel<<<(NCOL * KPAD + 255) / 256, 256, 0, stream>>>(U30, U20, U10, U31, U21, U11, U32, U22, U12, wsB);
  symcon_mfma<<<BATCH, 256, 0, stream>>>(x, idx, w, wsB, out);
}